// Round 1
// baseline (466.338 us; speedup 1.0000x reference)
//
#include <hip/hip_runtime.h>

// PLIF forward scan: v = beta*v + x_t; s = (v-1 >= 0); v *= (1-s)
// T=32 sequential in registers; B*N lanes fully parallel.
// Memory-bound: 268 MB in + 268 MB out => ~85 us floor at 6.3 TB/s.

#define T_STEPS 32

__global__ __launch_bounds__(256) void plif_fwd_kernel(
    const float4* __restrict__ x, const float* __restrict__ beta_raw,
    float4* __restrict__ out, int bn4)
{
    int i = blockIdx.x * blockDim.x + threadIdx.x;
    if (i >= bn4) return;

    // beta = sigmoid(beta_raw); precise expf to match reference trajectory
    float beta = 1.0f / (1.0f + expf(-beta_raw[0]));

    float4 v = make_float4(0.0f, 0.0f, 0.0f, 0.0f);

    int idx = i;
    #pragma unroll
    for (int t = 0; t < T_STEPS; ++t, idx += bn4) {
        float4 xt = x[idx];

        // v = beta*v + x_t  -- separate mul/add rounding (no fma contraction),
        // matching XLA's non-contracted mul+add HLO ops.
        v.x = __fadd_rn(__fmul_rn(beta, v.x), xt.x);
        v.y = __fadd_rn(__fmul_rn(beta, v.y), xt.y);
        v.z = __fadd_rn(__fmul_rn(beta, v.z), xt.z);
        v.w = __fadd_rn(__fmul_rn(beta, v.w), xt.w);

        // s = Heaviside(v - 1), reference op order: (v - one) >= 0
        float4 s;
        s.x = (__fadd_rn(v.x, -1.0f) >= 0.0f) ? 1.0f : 0.0f;
        s.y = (__fadd_rn(v.y, -1.0f) >= 0.0f) ? 1.0f : 0.0f;
        s.z = (__fadd_rn(v.z, -1.0f) >= 0.0f) ? 1.0f : 0.0f;
        s.w = (__fadd_rn(v.w, -1.0f) >= 0.0f) ? 1.0f : 0.0f;

        // hard reset: v = v * (1 - s); exact since s in {0,1}
        v.x *= (1.0f - s.x);
        v.y *= (1.0f - s.y);
        v.z *= (1.0f - s.z);
        v.w *= (1.0f - s.w);

        out[idx] = s;
    }
}

extern "C" void kernel_launch(void* const* d_in, const int* in_sizes, int n_in,
                              void* d_out, int out_size, void* d_ws, size_t ws_size,
                              hipStream_t stream) {
    const float* x        = (const float*)d_in[0];
    const float* beta_raw = (const float*)d_in[1];
    float* out            = (float*)d_out;

    int total = in_sizes[0];        // T*B*N = 67,108,864
    int bn    = total / T_STEPS;    // B*N   =  2,097,152
    int bn4   = bn / 4;             // float4 lanes = 524,288

    dim3 block(256);
    dim3 grid((bn4 + block.x - 1) / block.x);
    plif_fwd_kernel<<<grid, block, 0, stream>>>(
        (const float4*)x, beta_raw, (float4*)out, bn4);
}